// Round 9
// baseline (263.983 us; speedup 1.0000x reference)
//
#include <hip/hip_runtime.h>
#include <stdint.h>

#define BATCH  2
#define SEQ    2048
#define DMODEL 1024
#define NHEADS 16
#define DKH    64
#define MTOT   (BATCH*SEQ)   // 4096
#define VSTR   (SEQ + 32)    // padded V row stride

typedef unsigned short u16;
typedef __bf16 bf16x8 __attribute__((ext_vector_type(8)));
typedef float  f32x4  __attribute__((ext_vector_type(4)));

extern "C" __device__ float __ocml_native_exp2_f32(float);   // raw v_exp_f32

__device__ __forceinline__ u16 f2bf(float f) {
  union { float f; uint32_t u; } v; v.f = f;
  uint32_t u = v.u;
  return (u16)((u + 0x7FFFu + ((u >> 16) & 1u)) >> 16);   // RNE
}
__device__ __forceinline__ float bf2f(u16 h) {
  union { uint32_t u; float f; } v; v.u = (uint32_t)h << 16; return v.f;
}

// ---------------- fp32 -> bf16 converts -------------------------------------
__global__ void cvt_f32_bf16(const float* __restrict__ src, u16* __restrict__ dst) {
  size_t i = ((size_t)blockIdx.x * 256 + threadIdx.x) * 4;
  float4 f = *(const float4*)(src + i);
  ushort4 o;
  o.x = f2bf(f.x); o.y = f2bf(f.y); o.z = f2bf(f.z); o.w = f2bf(f.w);
  *(ushort4*)(dst + i) = o;
}
__global__ void cvt_w(const float* __restrict__ a, const float* __restrict__ b,
                      const float* __restrict__ c, const float* __restrict__ d,
                      u16* __restrict__ dst) {
  const float* srcs[4] = {a, b, c, d};
  const float* s = srcs[blockIdx.y];
  size_t i = ((size_t)blockIdx.x * 256 + threadIdx.x) * 4;
  float4 f = *(const float4*)(s + i);
  ushort4 o;
  o.x = f2bf(f.x); o.y = f2bf(f.y); o.z = f2bf(f.z); o.w = f2bf(f.w);
  *(ushort4*)(dst + (size_t)blockIdx.y * (DMODEL*DMODEL) + i) = o;
}

// ---------------- barrier-free GEMM wave core -------------------------------
// Each wave computes a private 64x64 C tile; A/B fragments loaded directly
// from global (no LDS, no __syncthreads, no lockstep). The 4 waves of a block
// share n0, so B (weight) fragments are L1-hot; A streams. Latency hidden by
// 12 independent waves/CU instead of barriered pipelining.
__device__ __forceinline__ void gemm_wave64(const u16* __restrict__ A,
                                            const u16* __restrict__ W,
                                            int m0, int n0, f32x4 acc[4][4]) {
  const int lane = threadIdx.x & 63;
  const int lrow = lane & 15;
  const int kq   = (lane >> 4) * 8;
  const u16* ab = A + (size_t)(m0 + lrow) * DMODEL + kq;
  const u16* wb = W + (size_t)(n0 + lrow) * DMODEL + kq;
  for (int k0 = 0; k0 < DMODEL; k0 += 64) {
    bf16x8 a[4][2], b[4][2];
    #pragma unroll
    for (int i = 0; i < 4; ++i)
      #pragma unroll
      for (int ks = 0; ks < 2; ++ks) {
        a[i][ks] = *(const bf16x8*)(ab + (size_t)i*16*DMODEL + k0 + ks*32);
        b[i][ks] = *(const bf16x8*)(wb + (size_t)i*16*DMODEL + k0 + ks*32);
      }
    #pragma unroll
    for (int ks = 0; ks < 2; ++ks)
      #pragma unroll
      for (int i = 0; i < 4; ++i)
        #pragma unroll
        for (int j = 0; j < 4; ++j)
          acc[i][j] = __builtin_amdgcn_mfma_f32_16x16x32_bf16(a[i][ks], b[j][ks], acc[i][j], 0, 0, 0);
  }
}

// ---------------- QKV projection, fused over blockIdx.z ---------------------
// grid (16, 16, 3) x 256 thr; wave w owns m0=(bx*4+w)*64, n0=by*64 (= head h).
__global__ __launch_bounds__(256, 3) void gemm_qkv(
    const u16* __restrict__ xb, const u16* __restrict__ wq,
    const u16* __restrict__ wk, const u16* __restrict__ wv,
    u16* __restrict__ q, u16* __restrict__ k, u16* __restrict__ v, float qscale) {
  const int z = blockIdx.z;
  const u16* W = (z == 0) ? wq : (z == 1) ? wk : wv;
  u16* out     = (z == 0) ? q  : (z == 1) ? k  : v;
  const float scale = (z == 0) ? qscale : 1.0f;
  const int wave = threadIdx.x >> 6;
  const int m0 = (blockIdx.x * 4 + wave) * 64;
  const int n0 = blockIdx.y * 64;

  f32x4 acc[4][4] = {};
  gemm_wave64(xb, W, m0, n0, acc);

  const int lane = threadIdx.x & 63;
  const int rb = (lane >> 4) * 4, cb = lane & 15;
  const int h = n0 >> 6;                       // whole tile is one head
  if (z == 2) {
    // V transposed (padded): pack 4 consecutive tokens into one ushort4
    #pragma unroll
    for (int i = 0; i < 4; ++i)
      #pragma unroll
      for (int j = 0; j < 4; ++j) {
        int row0 = m0 + i*16 + rb;
        int b_ = row0 >> 11, s0 = row0 & 2047;
        int d_ = j*16 + cb;
        ushort4 pk;
        pk.x = f2bf(acc[i][j][0]); pk.y = f2bf(acc[i][j][1]);
        pk.z = f2bf(acc[i][j][2]); pk.w = f2bf(acc[i][j][3]);
        *(ushort4*)&out[((size_t)(b_*NHEADS + h) * DKH + d_) * VSTR + s0] = pk;
      }
  } else {
    #pragma unroll
    for (int i = 0; i < 4; ++i)
      #pragma unroll
      for (int j = 0; j < 4; ++j)
        #pragma unroll
        for (int r = 0; r < 4; ++r) {
          int row = m0 + i*16 + rb + r;
          int b_ = row >> 11, s_ = row & 2047;
          int d_ = j*16 + cb;
          out[(((size_t)(b_*NHEADS + h) * SEQ + s_) << 6) + d_] =
              f2bf(acc[i][j][r] * scale);
        }
  }
}

// ---------------- output projection -> fp32, 32x64 per wave -----------------
// grid (32, 16) x 256 thr: 2048 independent wave-jobs (8 waves/CU).
__global__ __launch_bounds__(256, 4) void gemm_out(
    const u16* __restrict__ ab, const u16* __restrict__ wo, float* __restrict__ out) {
  const int wave = threadIdx.x >> 6;
  const int m0 = (blockIdx.x * 4 + wave) * 32;
  const int n0 = blockIdx.y * 64;
  const int lane = threadIdx.x & 63;
  const int lrow = lane & 15;
  const int kq   = (lane >> 4) * 8;

  f32x4 acc[2][4] = {};
  const u16* arow = ab + (size_t)(m0 + lrow) * DMODEL + kq;
  const u16* wrow = wo + (size_t)(n0 + lrow) * DMODEL + kq;
  for (int k0 = 0; k0 < DMODEL; k0 += 64) {
    bf16x8 a[2][2], b[4][2];
    #pragma unroll
    for (int ks = 0; ks < 2; ++ks) {
      #pragma unroll
      for (int i = 0; i < 2; ++i)
        a[i][ks] = *(const bf16x8*)(arow + (size_t)i*16*DMODEL + k0 + ks*32);
      #pragma unroll
      for (int j = 0; j < 4; ++j)
        b[j][ks] = *(const bf16x8*)(wrow + (size_t)j*16*DMODEL + k0 + ks*32);
    }
    #pragma unroll
    for (int ks = 0; ks < 2; ++ks)
      #pragma unroll
      for (int i = 0; i < 2; ++i)
        #pragma unroll
        for (int j = 0; j < 4; ++j)
          acc[i][j] = __builtin_amdgcn_mfma_f32_16x16x32_bf16(a[i][ks], b[j][ks], acc[i][j], 0, 0, 0);
  }

  const int rb = (lane >> 4) * 4, cb = lane & 15;
  #pragma unroll
  for (int i = 0; i < 2; ++i)
    #pragma unroll
    for (int j = 0; j < 4; ++j)
      #pragma unroll
      for (int r = 0; r < 4; ++r)
        out[(size_t)(m0 + i*16 + rb + r) * DMODEL + (n0 + j*16 + cb)]
            = acc[i][j][r];
}

// ---------------- flash attention v7: chunk<=12, static frag arrays ---------
#define PSTR 68
// job entry e = p*4 + c; LPT order: len-12 chunks (p desc), then len 11..1
__device__ const uint8_t JT[60] = {
  124,125,120,121,116,117,112,113,108,109,104,105,100,101,96,97,92,93,
  88,84,80,76,72,68,64,60,56,52,48,44,
  89,40, 85,36, 81,32, 126,77,28, 122,73,24, 118,69,20, 114,65,16,
  110,61,12, 106,57,8, 102,53,4, 98,49,0
};

__global__ __launch_bounds__(64, 2) void attn(
    const u16* __restrict__ Q, const u16* __restrict__ K,
    const u16* __restrict__ V, u16* __restrict__ O,
    u16* __restrict__ po, float* __restrict__ pl) {
  __shared__ __align__(16) u16 Ps[4][16 * PSTR];

  const int lane = threadIdx.x & 63;
  const int lrow = lane & 15;
  const int quad = lane >> 4;
  const int kq   = quad * 8;

  const int g  = blockIdx.x >> 5;
  const int bh = blockIdx.x & 31;
  const int e  = JT[g];
  const int p  = e >> 2, c = e & 3;
  const int lo = c * 12;
  const int hi = (p + 1 < lo + 12) ? p + 1 : lo + 12;

  const u16* Qg = Q + (size_t)bh * SEQ * DKH;
  const u16* Kg = K + (size_t)bh * SEQ * DKH;
  const u16* Vg = V + (size_t)bh * DKH * VSTR;

  bf16x8 aq[4][2];
  #pragma unroll
  for (int i = 0; i < 4; ++i)
    #pragma unroll
    for (int ks = 0; ks < 2; ++ks)
      aq[i][ks] = *(const bf16x8*)(Qg + (size_t)(64*p + 16*i + lrow) * DKH + ks*32 + kq);

  f32x4 o_acc[4][4] = {};
  float l_acc[4][4] = {};

  const u16* kbase = Kg + (size_t)lrow * DKH + kq;
  const u16* vbase = Vg + (size_t)lrow * VSTR + kq;

  for (int t = lo; t < hi; ++t) {
    bf16x8 kf[2][4], vf[2][4];
    #pragma unroll
    for (int ks = 0; ks < 2; ++ks)
      #pragma unroll
      for (int j = 0; j < 4; ++j) {
        kf[ks][j] = *(const bf16x8*)(kbase + (size_t)t*64*DKH + j*16*DKH + ks*32);
        vf[ks][j] = *(const bf16x8*)(vbase + t*64 + (size_t)j*16*VSTR + ks*32);
      }
    const bool mk = (t == p);

    #pragma unroll
    for (int i = 0; i < 4; ++i) {
      f32x4 s_acc[4] = {};
      #pragma unroll
      for (int ks = 0; ks < 2; ++ks)
        #pragma unroll
        for (int j = 0; j < 4; ++j)
          s_acc[j] = __builtin_amdgcn_mfma_f32_16x16x32_bf16(aq[i][ks], kf[ks][j], s_acc[j], 0, 0, 0);

      if (mk) {
        const int qloc = 16*i + quad*4;
        #pragma unroll
        for (int j = 0; j < 4; ++j) {
          int kloc = j*16 + lrow;
          #pragma unroll
          for (int r = 0; r < 4; ++r)
            if (kloc > qloc + r) s_acc[j][r] = -1e30f;
        }
      }

      #pragma unroll
      for (int j = 0; j < 4; ++j)
        #pragma unroll
        for (int r = 0; r < 4; ++r) {
          float pv = __ocml_native_exp2_f32(s_acc[j][r]);
          l_acc[i][r] += pv;
          union { float f; uint32_t u; } cv; cv.f = pv;
          Ps[i][(quad*4 + r) * PSTR + j*16 + lrow] = (u16)(cv.u >> 16);
        }

      #pragma unroll
      for (int ks = 0; ks < 2; ++ks) {
        bf16x8 ap = *(const bf16x8*)(&Ps[i][lrow * PSTR + ks*32 + kq]);
        #pragma unroll
        for (int j = 0; j < 4; ++j)
          o_acc[i][j] = __builtin_amdgcn_mfma_f32_16x16x32_bf16(ap, vf[ks][j], o_acc[i][j], 0, 0, 0);
      }
    }
  }

  float lr[4][4];
  #pragma unroll
  for (int i = 0; i < 4; ++i)
    #pragma unroll
    for (int r = 0; r < 4; ++r) {
      float sm = l_acc[i][r];
      #pragma unroll
      for (int d = 1; d < 16; d <<= 1) sm += __shfl_xor(sm, d, 64);
      lr[i][r] = sm;
    }

  if (p <= 11) {                       // single chunk: write final output
    const int h = bh & 15, b_ = bh >> 4;
    #pragma unroll
    for (int i = 0; i < 4; ++i)
      #pragma unroll
      for (int j = 0; j < 4; ++j)
        #pragma unroll
        for (int r = 0; r < 4; ++r) {
          int sg = 64*p + 16*i + quad*4 + r;
          O[(size_t)(b_ * SEQ + sg) * DMODEL + h * DKH + j*16 + lrow]
              = f2bf(o_acc[i][j][r] / lr[i][r]);
        }
  } else {                             // partial: po[slot][col][row]
    const int base = (p < 24) ? (p - 12) * 2 : 24 + (p - 24) * 3;
    const int slot = (base + c) * 32 + bh;
    #pragma unroll
    for (int i = 0; i < 4; ++i) {
      #pragma unroll
      for (int j = 0; j < 4; ++j) {
        ushort4 pk;
        pk.x = f2bf(o_acc[i][j][0]); pk.y = f2bf(o_acc[i][j][1]);
        pk.z = f2bf(o_acc[i][j][2]); pk.w = f2bf(o_acc[i][j][3]);
        *(ushort4*)&po[(size_t)slot * 4096 + (j*16 + lrow) * 64 + 16*i + quad*4] = pk;
      }
      if (lrow == 0)
        #pragma unroll
        for (int r = 0; r < 4; ++r)
          pl[slot * 64 + 16*i + quad*4 + r] = lr[i][r];
    }
  }
}

// ---------------- combine v2: parallel, unrolled, coalesced -----------------
__global__ __launch_bounds__(256) void combine(
    const u16* __restrict__ po, const float* __restrict__ pl, u16* __restrict__ ab) {
  __shared__ u16 Ls[64][68];
  const int b  = blockIdx.x;          // 0..639
  const int p  = 12 + (b >> 5);
  const int bh = b & 31;
  const int t  = threadIdx.x;
  const int col = t >> 2;             // 0..63
  const int r0  = (t & 3) * 16;       // 16-row slab
  const int base = (p < 24) ? (p - 12) * 2 : 24 + (p - 24) * 3;
  const int nc   = (p < 24) ? 2 : 3;

  float acc[16], lsum[16];
  {
    const size_t s0 = (size_t)(base * 32 + bh);
    const u16*   q0 = po + s0 * 4096 + col * 64 + r0;
    const float* l0 = pl + s0 * 64 + r0;
    #pragma unroll
    for (int q4 = 0; q4 < 4; ++q4) {
      ushort4 a = *(const ushort4*)(q0 + q4 * 4);
      ushort4 c2 = *(const ushort4*)(q0 + 32 * 4096 + q4 * 4);
      acc[q4*4+0] = bf2f(a.x) + bf2f(c2.x);
      acc[q4*4+1] = bf2f(a.y) + bf2f(c2.y);
      acc[q4*4+2] = bf2f(a.z) + bf2f(c2.z);
      acc[q4*4+3] = bf2f(a.w) + bf2f(c2.w);
      float4 f = *(const float4*)(l0 + q4 * 4);
      float4 g = *(const float4*)(l0 + 32 * 64 + q4 * 4);
      lsum[q4*4+0] = f.x + g.x; lsum[q4*4+1] = f.y + g.y;
      lsum[q4*4+2] = f.z + g.z; lsum[q4*4+3] = f.w + g.w;
    }
    if (nc == 3) {
      const u16*   q2 = q0 + (size_t)64 * 4096;
      const float* l2 = l0 + (size_t)64 * 64;
      #pragma unroll
      for (int q4 = 0; q4 < 4; ++q4) {
        ushort4 a = *(const ushort4*)(q2 + q4 * 4);
        acc[q4*4+0] += bf2f(a.x); acc[q4*4+1] += bf2f(a.y);
        acc[q4*4+2] += bf2f(a.z); acc[q4*4+3] += bf2f(a.w);
        float4 f = *(const float4*)(l2 + q4 * 4);
        lsum[q4*4+0] += f.x; lsum[q4*4+1] += f.y;
        lsum[q4*4+2] += f.z; lsum[q4*4+3] += f.w;
      }
    }
  }
  #pragma unroll
  for (int q = 0; q < 16; ++q)
    Ls[r0 + q][col] = f2bf(acc[q] / lsum[q]);
  __syncthreads();

  const int row = t >> 2;
  const int c0  = (t & 3) * 16;
  const int b_ = bh >> 4, h = bh & 15;
  u16* dst = ab + (size_t)(b_ * SEQ + 64 * p + row) * DMODEL + h * DKH + c0;
  #pragma unroll
  for (int q = 0; q < 16; q += 4)
    *(ushort4*)(dst + q) = *(const ushort4*)&Ls[row][c0 + q];
}

// ---------------- launcher ---------------------------------------------------
extern "C" void kernel_launch(void* const* d_in, const int* in_sizes, int n_in,
                              void* d_out, int out_size, void* d_ws, size_t ws_size,
                              hipStream_t stream) {
  const float* x  = (const float*)d_in[0];
  const float* Wq = (const float*)d_in[1];
  const float* Wk = (const float*)d_in[2];
  const float* Wv = (const float*)d_in[3];
  const float* Wo = (const float*)d_in[4];
  float* out = (float*)d_out;

  u16* xb  = (u16*)d_ws;                               // 4M u16
  u16* wqb = xb  + (size_t)MTOT * DMODEL;              // 1M each
  u16* wkb = wqb + (size_t)DMODEL * DMODEL;
  u16* wvb = wkb + (size_t)DMODEL * DMODEL;
  u16* wob = wvb + (size_t)DMODEL * DMODEL;            // @7M, must survive attn
  u16* qb  = wob + (size_t)DMODEL * DMODEL;            // [B,H,S,dk]
  u16* kb  = qb  + (size_t)MTOT * DMODEL;              // [B,H,S,dk]
  u16* vb  = kb  + (size_t)MTOT * DMODEL;              // [B,H,dk,VSTR]
  u16* ab  = vb  + (size_t)BATCH * NHEADS * DKH * VSTR;
  // partials alias the dead xb/wq/wk/wv region (consumed before attn):
  u16* po  = xb;
  float* pl = (float*)(po + (size_t)1536 * 4096);

  cvt_f32_bf16<<<MTOT * DMODEL / 1024, 256, 0, stream>>>(x, xb);
  cvt_w<<<dim3(DMODEL * DMODEL / 1024, 4), 256, 0, stream>>>(Wq, Wk, Wv, Wo, wqb);

  const float qscale = 0.125f * 1.44269504088896340736f;
  gemm_qkv<<<dim3(16, 16, 3), 256, 0, stream>>>(
      xb, wqb, wkb, wvb, qb, kb, vb, qscale);

  attn<<<1920, 64, 0, stream>>>(qb, kb, vb, ab, po, pl);
  combine<<<640, 256, 0, stream>>>(po, pl, ab);

  gemm_out<<<dim3(32, 16), 256, 0, stream>>>(ab, wob, out);
}

// Round 10
// 176.224 us; speedup vs baseline: 1.4980x; 1.4980x over previous
//
#include <hip/hip_runtime.h>
#include <stdint.h>

#define BATCH  2
#define SEQ    2048
#define DMODEL 1024
#define NHEADS 16
#define DKH    64
#define MTOT   (BATCH*SEQ)   // 4096
#define VSTR   (SEQ + 32)    // padded V row stride

typedef unsigned short u16;
typedef __bf16 bf16x8 __attribute__((ext_vector_type(8)));
typedef float  f32x4  __attribute__((ext_vector_type(4)));

extern "C" __device__ float __ocml_native_exp2_f32(float);   // raw v_exp_f32

__device__ __forceinline__ u16 f2bf(float f) {
  union { float f; uint32_t u; } v; v.f = f;
  uint32_t u = v.u;
  return (u16)((u + 0x7FFFu + ((u >> 16) & 1u)) >> 16);   // RNE
}
__device__ __forceinline__ float bf2f(u16 h) {
  union { uint32_t u; float f; } v; v.u = (uint32_t)h << 16; return v.f;
}

__device__ __forceinline__ void gld_lds16(const void* g, void* l) {
  __builtin_amdgcn_global_load_lds(
      (__attribute__((address_space(1))) void*)g,
      (__attribute__((address_space(3))) void*)l, 16, 0, 0);
}

// ---------------- fp32 -> bf16 converts -------------------------------------
__global__ void cvt_f32_bf16(const float* __restrict__ src, u16* __restrict__ dst) {
  size_t i = ((size_t)blockIdx.x * 256 + threadIdx.x) * 4;
  float4 f = *(const float4*)(src + i);
  ushort4 o;
  o.x = f2bf(f.x); o.y = f2bf(f.y); o.z = f2bf(f.z); o.w = f2bf(f.w);
  *(ushort4*)(dst + i) = o;
}
__global__ void cvt_w(const float* __restrict__ a, const float* __restrict__ b,
                      const float* __restrict__ c, const float* __restrict__ d,
                      u16* __restrict__ dst) {
  const float* srcs[4] = {a, b, c, d};
  const float* s = srcs[blockIdx.y];
  size_t i = ((size_t)blockIdx.x * 256 + threadIdx.x) * 4;
  float4 f = *(const float4*)(s + i);
  ushort4 o;
  o.x = f2bf(f.x); o.y = f2bf(f.y); o.z = f2bf(f.z); o.w = f2bf(f.w);
  *(ushort4*)(dst + (size_t)blockIdx.y * (DMODEL*DMODEL) + i) = o;
}

// ---------------- GEMM core: 128x64 block tile, XOR-swizzled LDS ------------
// A tile 128x64 (16KB), B tile 64x64 (8KB) -> 24KB/block -> 2-6 blocks/CU
// (vs 1-3 at 128x128): barrier drains overlap across independent blocks.
// LDS slot (row,c16) holds global chunk (row, c16^(row&7)); reads same XOR.
__device__ __forceinline__ void gemm_core64(const u16* A, const u16* W,
                                            int m0, int n0, f32x4 acc[4][2],
                                            u16* lA, u16* lB) {
  const int tid  = threadIdx.x;
  const int lane = tid & 63;
  const int lrow = lane & 15;
  const int quad = lane >> 4;
  const int wave = tid >> 6;
  const int wm   = (wave & 1) * 64;
  const int wn   = (wave >> 1) * 32;
  const int sx   = lrow & 7;            // read-side swizzle key

  for (int k0 = 0; k0 < DMODEL; k0 += 64) {
    #pragma unroll
    for (int r = 0; r < 4; ++r) {       // A: 128 rows, 4 rounds
      int off  = r * 4096 + tid * 16;
      int row  = off >> 7;
      int c16  = (off >> 4) & 7;
      int colb = (c16 ^ (row & 7)) << 4;
      gld_lds16((const char*)A + ((size_t)(m0 + row) * DMODEL + k0) * 2 + colb,
                (char*)lA + off);
    }
    #pragma unroll
    for (int r = 0; r < 2; ++r) {       // B: 64 rows, 2 rounds
      int off  = r * 4096 + tid * 16;
      int row  = off >> 7;
      int c16  = (off >> 4) & 7;
      int colb = (c16 ^ (row & 7)) << 4;
      gld_lds16((const char*)W + ((size_t)(n0 + row) * DMODEL + k0) * 2 + colb,
                (char*)lB + off);
    }
    __syncthreads();
    #pragma unroll
    for (int ks = 0; ks < 2; ++ks) {
      bf16x8 a[4], b[2];
      const int ro = ((((ks << 2) | quad) ^ sx) << 3);
      #pragma unroll
      for (int i = 0; i < 4; ++i)
        a[i] = *(const bf16x8*)(lA + (wm + i*16 + lrow) * 64 + ro);
      #pragma unroll
      for (int j = 0; j < 2; ++j)
        b[j] = *(const bf16x8*)(lB + (wn + j*16 + lrow) * 64 + ro);
      #pragma unroll
      for (int i = 0; i < 4; ++i)
        #pragma unroll
        for (int j = 0; j < 2; ++j)
          acc[i][j] = __builtin_amdgcn_mfma_f32_16x16x32_bf16(a[i], b[j], acc[i][j], 0, 0, 0);
    }
    __syncthreads();
  }
}

// ---------------- QKV projection, fused over blockIdx.z ---------------------
// grid (32,16,3): block = 128 tokens x 64 model-dims (one head).
__global__ __launch_bounds__(256, 3) void gemm_qkv(
    const u16* __restrict__ xb, const u16* __restrict__ wq,
    const u16* __restrict__ wk, const u16* __restrict__ wv,
    u16* __restrict__ q, u16* __restrict__ k, u16* __restrict__ v, float qscale) {
  __shared__ __align__(16) u16 lA[128 * 64];
  __shared__ __align__(16) u16 lB[64 * 64];
  const int z = blockIdx.z;
  const u16* W = (z == 0) ? wq : (z == 1) ? wk : wv;
  u16* out     = (z == 0) ? q  : (z == 1) ? k  : v;
  const float scale = (z == 0) ? qscale : 1.0f;
  const int m0 = blockIdx.x * 128, n0 = blockIdx.y * 64;
  f32x4 acc[4][2] = {};
  gemm_core64(xb, W, m0, n0, acc, lA, lB);

  const int lane = threadIdx.x & 63;
  const int wave = threadIdx.x >> 6;
  const int wm = (wave & 1) * 64, wn = (wave >> 1) * 32;
  const int rb = (lane >> 4) * 4, cb = lane & 15;
  const int h = n0 >> 6;                 // whole 64-wide tile is one head
  if (z == 2) {
    #pragma unroll
    for (int i = 0; i < 4; ++i)
      #pragma unroll
      for (int j = 0; j < 2; ++j) {
        int row0 = m0 + wm + i*16 + rb;
        int d_   = wn + j*16 + cb;       // 0..63 within head
        int b_ = row0 >> 11, s0 = row0 & 2047;
        ushort4 pk;
        pk.x = f2bf(acc[i][j][0]); pk.y = f2bf(acc[i][j][1]);
        pk.z = f2bf(acc[i][j][2]); pk.w = f2bf(acc[i][j][3]);
        *(ushort4*)&out[((size_t)(b_*NHEADS + h) * DKH + d_) * VSTR + s0] = pk;
      }
  } else {
    #pragma unroll
    for (int i = 0; i < 4; ++i)
      #pragma unroll
      for (int j = 0; j < 2; ++j)
        #pragma unroll
        for (int r = 0; r < 4; ++r) {
          int row = m0 + wm + i*16 + rb + r;
          int d_  = wn + j*16 + cb;
          int b_ = row >> 11, s_ = row & 2047;
          out[(((size_t)(b_*NHEADS + h) * SEQ + s_) << 6) + d_] =
              f2bf(acc[i][j][r] * scale);
        }
  }
}

// ---------------- output projection -> fp32 ---------------------------------
// grid (32,16): 512 blocks (2+/CU vs previous 256 = 1/CU full lockstep).
__global__ __launch_bounds__(256, 3) void gemm_out(
    const u16* __restrict__ ab, const u16* __restrict__ wo, float* __restrict__ out) {
  __shared__ __align__(16) u16 lA[128 * 64];
  __shared__ __align__(16) u16 lB[64 * 64];
  const int m0 = blockIdx.x * 128, n0 = blockIdx.y * 64;
  f32x4 acc[4][2] = {};
  gemm_core64(ab, wo, m0, n0, acc, lA, lB);

  const int lane = threadIdx.x & 63;
  const int wave = threadIdx.x >> 6;
  const int wm = (wave & 1) * 64, wn = (wave >> 1) * 32;
  const int rb = (lane >> 4) * 4, cb = lane & 15;
  #pragma unroll
  for (int i = 0; i < 4; ++i)
    #pragma unroll
    for (int j = 0; j < 2; ++j)
      #pragma unroll
      for (int r = 0; r < 4; ++r)
        out[(size_t)(m0 + wm + i*16 + rb + r) * DMODEL + (n0 + wn + j*16 + cb)]
            = acc[i][j][r];
}

// ---------------- flash attention v7: chunk<=12, static frag arrays ---------
#define PSTR 68
// job entry e = p*4 + c; LPT order: len-12 chunks (p desc), then len 11..1
__device__ const uint8_t JT[60] = {
  124,125,120,121,116,117,112,113,108,109,104,105,100,101,96,97,92,93,
  88,84,80,76,72,68,64,60,56,52,48,44,
  89,40, 85,36, 81,32, 126,77,28, 122,73,24, 118,69,20, 114,65,16,
  110,61,12, 106,57,8, 102,53,4, 98,49,0
};

__global__ __launch_bounds__(64, 2) void attn(
    const u16* __restrict__ Q, const u16* __restrict__ K,
    const u16* __restrict__ V, u16* __restrict__ O,
    u16* __restrict__ po, float* __restrict__ pl) {
  __shared__ __align__(16) u16 Ps[4][16 * PSTR];

  const int lane = threadIdx.x & 63;
  const int lrow = lane & 15;
  const int quad = lane >> 4;
  const int kq   = quad * 8;

  const int g  = blockIdx.x >> 5;
  const int bh = blockIdx.x & 31;
  const int e  = JT[g];
  const int p  = e >> 2, c = e & 3;
  const int lo = c * 12;
  const int hi = (p + 1 < lo + 12) ? p + 1 : lo + 12;

  const u16* Qg = Q + (size_t)bh * SEQ * DKH;
  const u16* Kg = K + (size_t)bh * SEQ * DKH;
  const u16* Vg = V + (size_t)bh * DKH * VSTR;

  bf16x8 aq[4][2];
  #pragma unroll
  for (int i = 0; i < 4; ++i)
    #pragma unroll
    for (int ks = 0; ks < 2; ++ks)
      aq[i][ks] = *(const bf16x8*)(Qg + (size_t)(64*p + 16*i + lrow) * DKH + ks*32 + kq);

  f32x4 o_acc[4][4] = {};
  float l_acc[4][4] = {};

  const u16* kbase = Kg + (size_t)lrow * DKH + kq;
  const u16* vbase = Vg + (size_t)lrow * VSTR + kq;

  for (int t = lo; t < hi; ++t) {
    bf16x8 kf[2][4], vf[2][4];
    #pragma unroll
    for (int ks = 0; ks < 2; ++ks)
      #pragma unroll
      for (int j = 0; j < 4; ++j) {
        kf[ks][j] = *(const bf16x8*)(kbase + (size_t)t*64*DKH + j*16*DKH + ks*32);
        vf[ks][j] = *(const bf16x8*)(vbase + t*64 + (size_t)j*16*VSTR + ks*32);
      }
    const bool mk = (t == p);

    #pragma unroll
    for (int i = 0; i < 4; ++i) {
      f32x4 s_acc[4] = {};
      #pragma unroll
      for (int ks = 0; ks < 2; ++ks)
        #pragma unroll
        for (int j = 0; j < 4; ++j)
          s_acc[j] = __builtin_amdgcn_mfma_f32_16x16x32_bf16(aq[i][ks], kf[ks][j], s_acc[j], 0, 0, 0);

      if (mk) {
        const int qloc = 16*i + quad*4;
        #pragma unroll
        for (int j = 0; j < 4; ++j) {
          int kloc = j*16 + lrow;
          #pragma unroll
          for (int r = 0; r < 4; ++r)
            if (kloc > qloc + r) s_acc[j][r] = -1e30f;
        }
      }

      #pragma unroll
      for (int j = 0; j < 4; ++j)
        #pragma unroll
        for (int r = 0; r < 4; ++r) {
          float pv = __ocml_native_exp2_f32(s_acc[j][r]);
          l_acc[i][r] += pv;
          union { float f; uint32_t u; } cv; cv.f = pv;
          Ps[i][(quad*4 + r) * PSTR + j*16 + lrow] = (u16)(cv.u >> 16);
        }

      #pragma unroll
      for (int ks = 0; ks < 2; ++ks) {
        bf16x8 ap = *(const bf16x8*)(&Ps[i][lrow * PSTR + ks*32 + kq]);
        #pragma unroll
        for (int j = 0; j < 4; ++j)
          o_acc[i][j] = __builtin_amdgcn_mfma_f32_16x16x32_bf16(ap, vf[ks][j], o_acc[i][j], 0, 0, 0);
      }
    }
  }

  float lr[4][4];
  #pragma unroll
  for (int i = 0; i < 4; ++i)
    #pragma unroll
    for (int r = 0; r < 4; ++r) {
      float sm = l_acc[i][r];
      #pragma unroll
      for (int d = 1; d < 16; d <<= 1) sm += __shfl_xor(sm, d, 64);
      lr[i][r] = sm;
    }

  if (p <= 11) {                       // single chunk: write final output
    const int h = bh & 15, b_ = bh >> 4;
    #pragma unroll
    for (int i = 0; i < 4; ++i)
      #pragma unroll
      for (int j = 0; j < 4; ++j)
        #pragma unroll
        for (int r = 0; r < 4; ++r) {
          int sg = 64*p + 16*i + quad*4 + r;
          O[(size_t)(b_ * SEQ + sg) * DMODEL + h * DKH + j*16 + lrow]
              = f2bf(o_acc[i][j][r] / lr[i][r]);
        }
  } else {                             // partial: po[slot][col][row]
    const int base = (p < 24) ? (p - 12) * 2 : 24 + (p - 24) * 3;
    const int slot = (base + c) * 32 + bh;
    #pragma unroll
    for (int i = 0; i < 4; ++i) {
      #pragma unroll
      for (int j = 0; j < 4; ++j) {
        ushort4 pk;
        pk.x = f2bf(o_acc[i][j][0]); pk.y = f2bf(o_acc[i][j][1]);
        pk.z = f2bf(o_acc[i][j][2]); pk.w = f2bf(o_acc[i][j][3]);
        *(ushort4*)&po[(size_t)slot * 4096 + (j*16 + lrow) * 64 + 16*i + quad*4] = pk;
      }
      if (lrow == 0)
        #pragma unroll
        for (int r = 0; r < 4; ++r)
          pl[slot * 64 + 16*i + quad*4 + r] = lr[i][r];
    }
  }
}

// ---------------- combine v2: parallel, unrolled, coalesced -----------------
__global__ __launch_bounds__(256) void combine(
    const u16* __restrict__ po, const float* __restrict__ pl, u16* __restrict__ ab) {
  __shared__ u16 Ls[64][68];
  const int b  = blockIdx.x;          // 0..639
  const int p  = 12 + (b >> 5);
  const int bh = b & 31;
  const int t  = threadIdx.x;
  const int col = t >> 2;             // 0..63
  const int r0  = (t & 3) * 16;       // 16-row slab
  const int base = (p < 24) ? (p - 12) * 2 : 24 + (p - 24) * 3;
  const int nc   = (p < 24) ? 2 : 3;

  float acc[16], lsum[16];
  {
    const size_t s0 = (size_t)(base * 32 + bh);
    const u16*   q0 = po + s0 * 4096 + col * 64 + r0;
    const float* l0 = pl + s0 * 64 + r0;
    #pragma unroll
    for (int q4 = 0; q4 < 4; ++q4) {
      ushort4 a = *(const ushort4*)(q0 + q4 * 4);
      ushort4 c2 = *(const ushort4*)(q0 + 32 * 4096 + q4 * 4);
      acc[q4*4+0] = bf2f(a.x) + bf2f(c2.x);
      acc[q4*4+1] = bf2f(a.y) + bf2f(c2.y);
      acc[q4*4+2] = bf2f(a.z) + bf2f(c2.z);
      acc[q4*4+3] = bf2f(a.w) + bf2f(c2.w);
      float4 f = *(const float4*)(l0 + q4 * 4);
      float4 g = *(const float4*)(l0 + 32 * 64 + q4 * 4);
      lsum[q4*4+0] = f.x + g.x; lsum[q4*4+1] = f.y + g.y;
      lsum[q4*4+2] = f.z + g.z; lsum[q4*4+3] = f.w + g.w;
    }
    if (nc == 3) {
      const u16*   q2 = q0 + (size_t)64 * 4096;
      const float* l2 = l0 + (size_t)64 * 64;
      #pragma unroll
      for (int q4 = 0; q4 < 4; ++q4) {
        ushort4 a = *(const ushort4*)(q2 + q4 * 4);
        acc[q4*4+0] += bf2f(a.x); acc[q4*4+1] += bf2f(a.y);
        acc[q4*4+2] += bf2f(a.z); acc[q4*4+3] += bf2f(a.w);
        float4 f = *(const float4*)(l2 + q4 * 4);
        lsum[q4*4+0] += f.x; lsum[q4*4+1] += f.y;
        lsum[q4*4+2] += f.z; lsum[q4*4+3] += f.w;
      }
    }
  }
  #pragma unroll
  for (int q = 0; q < 16; ++q)
    Ls[r0 + q][col] = f2bf(acc[q] / lsum[q]);
  __syncthreads();

  const int row = t >> 2;
  const int c0  = (t & 3) * 16;
  const int b_ = bh >> 4, h = bh & 15;
  u16* dst = ab + (size_t)(b_ * SEQ + 64 * p + row) * DMODEL + h * DKH + c0;
  #pragma unroll
  for (int q = 0; q < 16; q += 4)
    *(ushort4*)(dst + q) = *(const ushort4*)&Ls[row][c0 + q];
}

// ---------------- launcher ---------------------------------------------------
extern "C" void kernel_launch(void* const* d_in, const int* in_sizes, int n_in,
                              void* d_out, int out_size, void* d_ws, size_t ws_size,
                              hipStream_t stream) {
  const float* x  = (const float*)d_in[0];
  const float* Wq = (const float*)d_in[1];
  const float* Wk = (const float*)d_in[2];
  const float* Wv = (const float*)d_in[3];
  const float* Wo = (const float*)d_in[4];
  float* out = (float*)d_out;

  u16* xb  = (u16*)d_ws;                               // 4M u16
  u16* wqb = xb  + (size_t)MTOT * DMODEL;              // 1M each
  u16* wkb = wqb + (size_t)DMODEL * DMODEL;
  u16* wvb = wkb + (size_t)DMODEL * DMODEL;
  u16* wob = wvb + (size_t)DMODEL * DMODEL;            // @7M, must survive attn
  u16* qb  = wob + (size_t)DMODEL * DMODEL;            // [B,H,S,dk]
  u16* kb  = qb  + (size_t)MTOT * DMODEL;              // [B,H,S,dk]
  u16* vb  = kb  + (size_t)MTOT * DMODEL;              // [B,H,dk,VSTR]
  u16* ab  = vb  + (size_t)BATCH * NHEADS * DKH * VSTR;
  // partials alias the dead xb/wq/wk/wv region (consumed before attn):
  u16* po  = xb;
  float* pl = (float*)(po + (size_t)1536 * 4096);

  cvt_f32_bf16<<<MTOT * DMODEL / 1024, 256, 0, stream>>>(x, xb);
  cvt_w<<<dim3(DMODEL * DMODEL / 1024, 4), 256, 0, stream>>>(Wq, Wk, Wv, Wo, wqb);

  const float qscale = 0.125f * 1.44269504088896340736f;
  gemm_qkv<<<dim3(32, 16, 3), 256, 0, stream>>>(
      xb, wqb, wkb, wvb, qb, kb, vb, qscale);

  attn<<<1920, 64, 0, stream>>>(qb, kb, vb, ab, po, pl);
  combine<<<640, 256, 0, stream>>>(po, pl, ab);

  gemm_out<<<dim3(32, 16), 256, 0, stream>>>(ab, wob, out);
}

// Round 11
// 171.344 us; speedup vs baseline: 1.5407x; 1.0285x over previous
//
#include <hip/hip_runtime.h>
#include <stdint.h>

#define BATCH  2
#define SEQ    2048
#define DMODEL 1024
#define NHEADS 16
#define DKH    64
#define MTOT   (BATCH*SEQ)   // 4096
#define VSTR   (SEQ + 32)    // padded V row stride

typedef unsigned short u16;
typedef __bf16 bf16x8 __attribute__((ext_vector_type(8)));
typedef float  f32x4  __attribute__((ext_vector_type(4)));

extern "C" __device__ float __ocml_native_exp2_f32(float);   // raw v_exp_f32

__device__ __forceinline__ u16 f2bf(float f) {
  union { float f; uint32_t u; } v; v.f = f;
  uint32_t u = v.u;
  return (u16)((u + 0x7FFFu + ((u >> 16) & 1u)) >> 16);   // RNE
}
__device__ __forceinline__ float bf2f(u16 h) {
  union { uint32_t u; float f; } v; v.u = (uint32_t)h << 16; return v.f;
}

__device__ __forceinline__ void gld_lds16(const void* g, void* l) {
  __builtin_amdgcn_global_load_lds(
      (__attribute__((address_space(1))) void*)g,
      (__attribute__((address_space(3))) void*)l, 16, 0, 0);
}

// ---------------- fp32 -> bf16 converts -------------------------------------
__global__ void cvt_f32_bf16(const float* __restrict__ src, u16* __restrict__ dst) {
  size_t i = ((size_t)blockIdx.x * 256 + threadIdx.x) * 4;
  float4 f = *(const float4*)(src + i);
  ushort4 o;
  o.x = f2bf(f.x); o.y = f2bf(f.y); o.z = f2bf(f.z); o.w = f2bf(f.w);
  *(ushort4*)(dst + i) = o;
}
__global__ void cvt_w(const float* __restrict__ a, const float* __restrict__ b,
                      const float* __restrict__ c, const float* __restrict__ d,
                      u16* __restrict__ dst) {
  const float* srcs[4] = {a, b, c, d};
  const float* s = srcs[blockIdx.y];
  size_t i = ((size_t)blockIdx.x * 256 + threadIdx.x) * 4;
  float4 f = *(const float4*)(s + i);
  ushort4 o;
  o.x = f2bf(f.x); o.y = f2bf(f.y); o.z = f2bf(f.z); o.w = f2bf(f.w);
  *(ushort4*)(dst + (size_t)blockIdx.y * (DMODEL*DMODEL) + i) = o;
}

// ---------------- fused QKV GEMM: stage A once, 3 B tiles -------------------
// grid (32,16) x 256 thr. Block = 128 tokens x 64 dims (one head) for all of
// Q,K,V: A tile (16KB) staged ONCE per k-step + 3 B tiles (24KB) -> 48 MFMA
// per barrier (vs 16 in the per-z version), A global traffic cut 3x.
// XOR-swizzled LDS as before (conflict-free reads, verified R8: conflicts=0).
__global__ __launch_bounds__(256, 3) void gemm_qkv(
    const u16* __restrict__ xb, const u16* __restrict__ wq,
    const u16* __restrict__ wk, const u16* __restrict__ wv,
    u16* __restrict__ q, u16* __restrict__ k, u16* __restrict__ v, float qscale) {
  __shared__ __align__(16) u16 lA[128 * 64];
  __shared__ __align__(16) u16 lB[3][64 * 64];

  const int tid  = threadIdx.x;
  const int lane = tid & 63;
  const int lrow = lane & 15;
  const int quad = lane >> 4;
  const int wave = tid >> 6;
  const int wm   = (wave & 1) * 64;
  const int wn   = (wave >> 1) * 32;
  const int sx   = lrow & 7;
  const int m0 = blockIdx.x * 128, n0 = blockIdx.y * 64;
  const u16* Ws[3] = {wq, wk, wv};

  f32x4 acc[3][4][2] = {};

  for (int k0 = 0; k0 < DMODEL; k0 += 64) {
    #pragma unroll
    for (int r = 0; r < 4; ++r) {       // A: 128 rows
      int off  = r * 4096 + tid * 16;
      int row  = off >> 7;
      int c16  = (off >> 4) & 7;
      int colb = (c16 ^ (row & 7)) << 4;
      gld_lds16((const char*)xb + ((size_t)(m0 + row) * DMODEL + k0) * 2 + colb,
                (char*)lA + off);
    }
    #pragma unroll
    for (int z = 0; z < 3; ++z)
      #pragma unroll
      for (int r = 0; r < 2; ++r) {     // B: 64 rows each
        int off  = r * 4096 + tid * 16;
        int row  = off >> 7;
        int c16  = (off >> 4) & 7;
        int colb = (c16 ^ (row & 7)) << 4;
        gld_lds16((const char*)Ws[z] + ((size_t)(n0 + row) * DMODEL + k0) * 2 + colb,
                  (char*)&lB[z][0] + off);
      }
    __syncthreads();
    #pragma unroll
    for (int ks = 0; ks < 2; ++ks) {
      const int ro = ((((ks << 2) | quad) ^ sx) << 3);
      bf16x8 a[4], b[3][2];
      #pragma unroll
      for (int i = 0; i < 4; ++i)
        a[i] = *(const bf16x8*)(lA + (wm + i*16 + lrow) * 64 + ro);
      #pragma unroll
      for (int z = 0; z < 3; ++z)
        #pragma unroll
        for (int j = 0; j < 2; ++j)
          b[z][j] = *(const bf16x8*)(&lB[z][0] + (wn + j*16 + lrow) * 64 + ro);
      #pragma unroll
      for (int z = 0; z < 3; ++z)
        #pragma unroll
        for (int i = 0; i < 4; ++i)
          #pragma unroll
          for (int j = 0; j < 2; ++j)
            acc[z][i][j] = __builtin_amdgcn_mfma_f32_16x16x32_bf16(a[i], b[z][j], acc[z][i][j], 0, 0, 0);
    }
    __syncthreads();
  }

  const int rb = quad * 4, cb = lrow;
  const int h  = blockIdx.y;
  u16* outs[3] = {q, k, v};
  #pragma unroll
  for (int z = 0; z < 3; ++z) {
    u16* out = outs[z];
    if (z == 2) {
      #pragma unroll
      for (int i = 0; i < 4; ++i)
        #pragma unroll
        for (int j = 0; j < 2; ++j) {
          int row0 = m0 + wm + i*16 + rb;
          int d_   = wn + j*16 + cb;
          int b_ = row0 >> 11, s0 = row0 & 2047;
          ushort4 pk;
          pk.x = f2bf(acc[z][i][j][0]); pk.y = f2bf(acc[z][i][j][1]);
          pk.z = f2bf(acc[z][i][j][2]); pk.w = f2bf(acc[z][i][j][3]);
          *(ushort4*)&out[((size_t)(b_*NHEADS + h) * DKH + d_) * VSTR + s0] = pk;
        }
    } else {
      const float scale = (z == 0) ? qscale : 1.0f;
      #pragma unroll
      for (int i = 0; i < 4; ++i)
        #pragma unroll
        for (int j = 0; j < 2; ++j)
          #pragma unroll
          for (int r = 0; r < 4; ++r) {
            int row = m0 + wm + i*16 + rb + r;
            int d_  = wn + j*16 + cb;
            int b_ = row >> 11, s_ = row & 2047;
            out[(((size_t)(b_*NHEADS + h) * SEQ + s_) << 6) + d_] =
                f2bf(acc[z][i][j][r] * scale);
          }
    }
  }
}

// ---------------- GEMM core: 128x64 block tile (for gemm_out) ---------------
__device__ __forceinline__ void gemm_core64(const u16* A, const u16* W,
                                            int m0, int n0, f32x4 acc[4][2],
                                            u16* lA, u16* lB) {
  const int tid  = threadIdx.x;
  const int lane = tid & 63;
  const int lrow = lane & 15;
  const int quad = lane >> 4;
  const int wave = tid >> 6;
  const int wm   = (wave & 1) * 64;
  const int wn   = (wave >> 1) * 32;
  const int sx   = lrow & 7;

  for (int k0 = 0; k0 < DMODEL; k0 += 64) {
    #pragma unroll
    for (int r = 0; r < 4; ++r) {
      int off  = r * 4096 + tid * 16;
      int row  = off >> 7;
      int c16  = (off >> 4) & 7;
      int colb = (c16 ^ (row & 7)) << 4;
      gld_lds16((const char*)A + ((size_t)(m0 + row) * DMODEL + k0) * 2 + colb,
                (char*)lA + off);
    }
    #pragma unroll
    for (int r = 0; r < 2; ++r) {
      int off  = r * 4096 + tid * 16;
      int row  = off >> 7;
      int c16  = (off >> 4) & 7;
      int colb = (c16 ^ (row & 7)) << 4;
      gld_lds16((const char*)W + ((size_t)(n0 + row) * DMODEL + k0) * 2 + colb,
                (char*)lB + off);
    }
    __syncthreads();
    #pragma unroll
    for (int ks = 0; ks < 2; ++ks) {
      bf16x8 a[4], b[2];
      const int ro = ((((ks << 2) | quad) ^ sx) << 3);
      #pragma unroll
      for (int i = 0; i < 4; ++i)
        a[i] = *(const bf16x8*)(lA + (wm + i*16 + lrow) * 64 + ro);
      #pragma unroll
      for (int j = 0; j < 2; ++j)
        b[j] = *(const bf16x8*)(lB + (wn + j*16 + lrow) * 64 + ro);
      #pragma unroll
      for (int i = 0; i < 4; ++i)
        #pragma unroll
        for (int j = 0; j < 2; ++j)
          acc[i][j] = __builtin_amdgcn_mfma_f32_16x16x32_bf16(a[i], b[j], acc[i][j], 0, 0, 0);
    }
    __syncthreads();
  }
}

// ---------------- output projection -> fp32 ---------------------------------
__global__ __launch_bounds__(256, 3) void gemm_out(
    const u16* __restrict__ ab, const u16* __restrict__ wo, float* __restrict__ out) {
  __shared__ __align__(16) u16 lA[128 * 64];
  __shared__ __align__(16) u16 lB[64 * 64];
  const int m0 = blockIdx.x * 128, n0 = blockIdx.y * 64;
  f32x4 acc[4][2] = {};
  gemm_core64(ab, wo, m0, n0, acc, lA, lB);

  const int lane = threadIdx.x & 63;
  const int wave = threadIdx.x >> 6;
  const int wm = (wave & 1) * 64, wn = (wave >> 1) * 32;
  const int rb = (lane >> 4) * 4, cb = lane & 15;
  #pragma unroll
  for (int i = 0; i < 4; ++i)
    #pragma unroll
    for (int j = 0; j < 2; ++j)
      #pragma unroll
      for (int r = 0; r < 4; ++r)
        out[(size_t)(m0 + wm + i*16 + rb + r) * DMODEL + (n0 + wn + j*16 + cb)]
            = acc[i][j][r];
}

// ---------------- flash attention v8: chunk<=8, 2560 jobs -------------------
// 64 Q rows/wave; chunks of <=8 K-tiles -> 80 jobs/bh (LPT table), 2560
// one-wave blocks (~10/CU resident vs 7.5): more latency-hiding waves and
// shorter (<=8-tile) serial chains. Partials in dedicated ws (no aliasing).
#define PSTR 68
// job entry e = p*4 + c, LPT order: 52 len-8 jobs then len 7..1 (4 each)
__device__ const uint8_t JT[80] = {
  124,125,126,127, 120,121,122, 116,117,118, 112,113,114, 108,109,110,
  104,105,106, 100,101,102, 96,97,98, 92,93,94, 88,89, 84,85, 80,81,
  76,77, 72,73, 68,69, 64,65, 60,61, 56, 52, 48, 44, 40, 36, 32, 28,
  123,90,57,24, 119,86,53,20, 115,82,49,16, 111,78,45,12,
  107,74,41,8, 103,70,37,4, 99,66,33,0
};

__global__ __launch_bounds__(64, 2) void attn(
    const u16* __restrict__ Q, const u16* __restrict__ K,
    const u16* __restrict__ V, u16* __restrict__ O,
    u16* __restrict__ po, float* __restrict__ pl) {
  __shared__ __align__(16) u16 Ps[4][16 * PSTR];

  const int lane = threadIdx.x & 63;
  const int lrow = lane & 15;
  const int quad = lane >> 4;
  const int kq   = quad * 8;

  const int g  = blockIdx.x >> 5;
  const int bh = blockIdx.x & 31;
  const int e  = JT[g];
  const int p  = e >> 2, c = e & 3;
  const int lo = c * 8;
  const int hi = (p + 1 < lo + 8) ? p + 1 : lo + 8;

  const u16* Qg = Q + (size_t)bh * SEQ * DKH;
  const u16* Kg = K + (size_t)bh * SEQ * DKH;
  const u16* Vg = V + (size_t)bh * DKH * VSTR;

  bf16x8 aq[4][2];
  #pragma unroll
  for (int i = 0; i < 4; ++i)
    #pragma unroll
    for (int ks = 0; ks < 2; ++ks)
      aq[i][ks] = *(const bf16x8*)(Qg + (size_t)(64*p + 16*i + lrow) * DKH + ks*32 + kq);

  f32x4 o_acc[4][4] = {};
  float l_acc[4][4] = {};

  const u16* kbase = Kg + (size_t)lrow * DKH + kq;
  const u16* vbase = Vg + (size_t)lrow * VSTR + kq;

  for (int t = lo; t < hi; ++t) {
    bf16x8 kf[2][4], vf[2][4];
    #pragma unroll
    for (int ks = 0; ks < 2; ++ks)
      #pragma unroll
      for (int j = 0; j < 4; ++j) {
        kf[ks][j] = *(const bf16x8*)(kbase + (size_t)t*64*DKH + j*16*DKH + ks*32);
        vf[ks][j] = *(const bf16x8*)(vbase + t*64 + (size_t)j*16*VSTR + ks*32);
      }
    const bool mk = (t == p);

    #pragma unroll
    for (int i = 0; i < 4; ++i) {
      f32x4 s_acc[4] = {};
      #pragma unroll
      for (int ks = 0; ks < 2; ++ks)
        #pragma unroll
        for (int j = 0; j < 4; ++j)
          s_acc[j] = __builtin_amdgcn_mfma_f32_16x16x32_bf16(aq[i][ks], kf[ks][j], s_acc[j], 0, 0, 0);

      if (mk) {
        const int qloc = 16*i + quad*4;
        #pragma unroll
        for (int j = 0; j < 4; ++j) {
          int kloc = j*16 + lrow;
          #pragma unroll
          for (int r = 0; r < 4; ++r)
            if (kloc > qloc + r) s_acc[j][r] = -1e30f;
        }
      }

      #pragma unroll
      for (int j = 0; j < 4; ++j)
        #pragma unroll
        for (int r = 0; r < 4; ++r) {
          float pv = __ocml_native_exp2_f32(s_acc[j][r]);
          l_acc[i][r] += pv;
          union { float f; uint32_t u; } cv; cv.f = pv;
          Ps[i][(quad*4 + r) * PSTR + j*16 + lrow] = (u16)(cv.u >> 16);
        }

      #pragma unroll
      for (int ks = 0; ks < 2; ++ks) {
        bf16x8 ap = *(const bf16x8*)(&Ps[i][lrow * PSTR + ks*32 + kq]);
        #pragma unroll
        for (int j = 0; j < 4; ++j)
          o_acc[i][j] = __builtin_amdgcn_mfma_f32_16x16x32_bf16(ap, vf[ks][j], o_acc[i][j], 0, 0, 0);
      }
    }
  }

  float lr[4][4];
  #pragma unroll
  for (int i = 0; i < 4; ++i)
    #pragma unroll
    for (int r = 0; r < 4; ++r) {
      float sm = l_acc[i][r];
      #pragma unroll
      for (int d = 1; d < 16; d <<= 1) sm += __shfl_xor(sm, d, 64);
      lr[i][r] = sm;
    }

  if (p <= 7) {                        // single chunk: write final output
    const int h = bh & 15, b_ = bh >> 4;
    #pragma unroll
    for (int i = 0; i < 4; ++i)
      #pragma unroll
      for (int j = 0; j < 4; ++j)
        #pragma unroll
        for (int r = 0; r < 4; ++r) {
          int sg = 64*p + 16*i + quad*4 + r;
          O[(size_t)(b_ * SEQ + sg) * DMODEL + h * DKH + j*16 + lrow]
              = f2bf(o_acc[i][j][r] / lr[i][r]);
        }
  } else {                             // partial: po[slot][col][row]
    const int base = (p < 16) ? (p - 8) * 2
                   : (p < 24) ? 16 + (p - 16) * 3
                   :            40 + (p - 24) * 4;
    const int slot = (base + c) * 32 + bh;
    #pragma unroll
    for (int i = 0; i < 4; ++i) {
      #pragma unroll
      for (int j = 0; j < 4; ++j) {
        ushort4 pk;
        pk.x = f2bf(o_acc[i][j][0]); pk.y = f2bf(o_acc[i][j][1]);
        pk.z = f2bf(o_acc[i][j][2]); pk.w = f2bf(o_acc[i][j][3]);
        *(ushort4*)&po[(size_t)slot * 4096 + (j*16 + lrow) * 64 + 16*i + quad*4] = pk;
      }
      if (lrow == 0)
        #pragma unroll
        for (int r = 0; r < 4; ++r)
          pl[slot * 64 + 16*i + quad*4 + r] = lr[i][r];
    }
  }
}

// ---------------- combine chunk-partials for strips p>=8 --------------------
__global__ __launch_bounds__(256) void combine(
    const u16* __restrict__ po, const float* __restrict__ pl, u16* __restrict__ ab) {
  __shared__ u16 Ls[64][68];
  const int b  = blockIdx.x;          // 0..767
  const int p  = 8 + (b >> 5);
  const int bh = b & 31;
  const int t  = threadIdx.x;
  const int col = t >> 2;             // 0..63
  const int r0  = (t & 3) * 16;       // 16-row slab
  const int base = (p < 16) ? (p - 8) * 2
                 : (p < 24) ? 16 + (p - 16) * 3
                 :            40 + (p - 24) * 4;
  const int nc   = (p < 16) ? 2 : (p < 24) ? 3 : 4;

  float acc[16], lsum[16];
  const size_t s0 = (size_t)(base * 32 + bh);
  const u16*   q0 = po + s0 * 4096 + col * 64 + r0;
  const float* l0 = pl + s0 * 64 + r0;
  #pragma unroll
  for (int q4 = 0; q4 < 4; ++q4) {
    ushort4 a  = *(const ushort4*)(q0 + q4 * 4);
    ushort4 c2 = *(const ushort4*)(q0 + (size_t)32 * 4096 + q4 * 4);
    acc[q4*4+0] = bf2f(a.x) + bf2f(c2.x);
    acc[q4*4+1] = bf2f(a.y) + bf2f(c2.y);
    acc[q4*4+2] = bf2f(a.z) + bf2f(c2.z);
    acc[q4*4+3] = bf2f(a.w) + bf2f(c2.w);
    float4 f = *(const float4*)(l0 + q4 * 4);
    float4 g = *(const float4*)(l0 + 32 * 64 + q4 * 4);
    lsum[q4*4+0] = f.x + g.x; lsum[q4*4+1] = f.y + g.y;
    lsum[q4*4+2] = f.z + g.z; lsum[q4*4+3] = f.w + g.w;
  }
  if (nc >= 3) {
    #pragma unroll
    for (int q4 = 0; q4 < 4; ++q4) {
      ushort4 a = *(const ushort4*)(q0 + (size_t)64 * 4096 + q4 * 4);
      acc[q4*4+0] += bf2f(a.x); acc[q4*4+1] += bf2f(a.y);
      acc[q4*4+2] += bf2f(a.z); acc[q4*4+3] += bf2f(a.w);
      float4 f = *(const float4*)(l0 + 64 * 64 + q4 * 4);
      lsum[q4*4+0] += f.x; lsum[q4*4+1] += f.y;
      lsum[q4*4+2] += f.z; lsum[q4*4+3] += f.w;
    }
  }
  if (nc == 4) {
    #pragma unroll
    for (int q4 = 0; q4 < 4; ++q4) {
      ushort4 a = *(const ushort4*)(q0 + (size_t)96 * 4096 + q4 * 4);
      acc[q4*4+0] += bf2f(a.x); acc[q4*4+1] += bf2f(a.y);
      acc[q4*4+2] += bf2f(a.z); acc[q4*4+3] += bf2f(a.w);
      float4 f = *(const float4*)(l0 + 96 * 64 + q4 * 4);
      lsum[q4*4+0] += f.x; lsum[q4*4+1] += f.y;
      lsum[q4*4+2] += f.z; lsum[q4*4+3] += f.w;
    }
  }
  #pragma unroll
  for (int q = 0; q < 16; ++q)
    Ls[r0 + q][col] = f2bf(acc[q] / lsum[q]);
  __syncthreads();

  const int row = t >> 2;
  const int c0  = (t & 3) * 16;
  const int b_ = bh >> 4, h = bh & 15;
  u16* dst = ab + (size_t)(b_ * SEQ + 64 * p + row) * DMODEL + h * DKH + c0;
  #pragma unroll
  for (int q = 0; q < 16; q += 4)
    *(ushort4*)(dst + q) = *(const ushort4*)&Ls[row][c0 + q];
}

// ---------------- launcher ---------------------------------------------------
extern "C" void kernel_launch(void* const* d_in, const int* in_sizes, int n_in,
                              void* d_out, int out_size, void* d_ws, size_t ws_size,
                              hipStream_t stream) {
  const float* x  = (const float*)d_in[0];
  const float* Wq = (const float*)d_in[1];
  const float* Wk = (const float*)d_in[2];
  const float* Wv = (const float*)d_in[3];
  const float* Wo = (const float*)d_in[4];
  float* out = (float*)d_out;

  u16* xb  = (u16*)d_ws;                               // 4M u16
  u16* wqb = xb  + (size_t)MTOT * DMODEL;              // 1M each
  u16* wkb = wqb + (size_t)DMODEL * DMODEL;
  u16* wvb = wkb + (size_t)DMODEL * DMODEL;
  u16* wob = wvb + (size_t)DMODEL * DMODEL;
  u16* qb  = wob + (size_t)DMODEL * DMODEL;            // [B,H,S,dk]
  u16* kb  = qb  + (size_t)MTOT * DMODEL;              // [B,H,S,dk]
  u16* vb  = kb  + (size_t)MTOT * DMODEL;              // [B,H,dk,VSTR]
  u16* ab  = vb  + (size_t)BATCH * NHEADS * DKH * VSTR;
  u16* po  = ab  + (size_t)MTOT * DMODEL;              // 2304 slots x 4096 u16
  float* pl = (float*)(po + (size_t)2304 * 4096);      // 2304 x 64 f32

  cvt_f32_bf16<<<MTOT * DMODEL / 1024, 256, 0, stream>>>(x, xb);
  cvt_w<<<dim3(DMODEL * DMODEL / 1024, 4), 256, 0, stream>>>(Wq, Wk, Wv, Wo, wqb);

  const float qscale = 0.125f * 1.44269504088896340736f;
  gemm_qkv<<<dim3(32, 16), 256, 0, stream>>>(
      xb, wqb, wkb, wvb, qb, kb, vb, qscale);

  attn<<<2560, 64, 0, stream>>>(qb, kb, vb, ab, po, pl);
  combine<<<768, 256, 0, stream>>>(po, pl, ab);

  gemm_out<<<dim3(32, 16), 256, 0, stream>>>(ab, wob, out);
}